// Round 8
// baseline (781.231 us; speedup 1.0000x reference)
//
#include <hip/hip_runtime.h>
#include <cmath>

// B=2, S=2048, E=2048, H=16, D=128, M=B*S=4096, F=2E=4096
// GEMMs: 256x256 tile, BK=64, 512 threads (8 waves 2Mx4N), 128 KiB
// double-buffered LDS with st_16x32 swizzle, m201 8-phase schedule.
// Round-8: attention reverted to KVBLK=64 / 256-thread / 512-block
// structure (R7's 8-wave KVBLK=128 regressed: 1 block/CU, no overlap),
// now with flat power-of-2 LDS strides + XOR bank swizzle
// (col ^ ((row&7)<<3)) on K/V/P and the O-transpose -> 48 KB LDS,
// 3 blocks/CU, ~2-way banks everywhere (was ~4-way, 6.2M conflicts).

typedef _Float16 half8 __attribute__((ext_vector_type(8)));
typedef _Float16 half4v __attribute__((ext_vector_type(4)));
typedef float float4v __attribute__((ext_vector_type(4)));

__device__ inline void load_lds16(const _Float16* g, _Float16* l) {
  __builtin_amdgcn_global_load_lds(
      (const __attribute__((address_space(1))) void*)g,
      (__attribute__((address_space(3))) void*)l, 16, 0, 0);
}

// ---------------- fp32 -> fp16 convert (up to 4 arrays per launch) -------
__global__ void cvt_kernel(const float* __restrict__ s0, const float* __restrict__ s1,
                           const float* __restrict__ s2, const float* __restrict__ s3,
                           _Float16* d0, _Float16* d1, _Float16* d2, _Float16* d3,
                           int n0, int n1, int n2, int n3, float sc1) {
  const float* s;
  _Float16* d;
  int n;
  float sc = 1.0f;
  switch (blockIdx.y) {
    case 0: s = s0; d = d0; n = n0; break;
    case 1: s = s1; d = d1; n = n1; sc = sc1; break;
    case 2: s = s2; d = d2; n = n2; break;
    default: s = s3; d = d3; n = n3; break;
  }
  const int step = gridDim.x * 256 * 4;
  for (int i = (blockIdx.x * 256 + threadIdx.x) * 4; i < n; i += step) {
    float4v v = *(const float4v*)&s[i];
    half4v h;
#pragma unroll
    for (int e = 0; e < 4; e++) h[e] = (_Float16)(v[e] * sc);
    *(half4v*)&d[i] = h;
  }
}

// ---------------- 8-phase 256x256 GEMM core (round-2 schedule) -----------
__device__ __forceinline__ void gemm8_core(
    const _Float16* __restrict__ A, const _Float16* __restrict__ B, int Kloop,
    int Kstride, int bm, int bn, _Float16* lds, float4v acc[8][4]) {
  const int tid = threadIdx.x;
  const int w = tid >> 6, lane = tid & 63;
  const int l16 = lane & 15, quad = lane >> 4;
  const int srow = w * 16 + (lane >> 2);
  const int clocal = ((lane & 3) * 8) ^ ((lane & 32) ? 16 : 0);
  int rdh = (l16 << 5) + (quad << 3);
  rdh ^= (l16 & 8) << 1;  // st_16x32: ^32B when row&8

  const _Float16* pA0 = A + (size_t)(bm + srow) * Kstride + clocal;
  const _Float16* pA1 = A + (size_t)(bm + 128 + srow) * Kstride + clocal;
  const _Float16* pB0 = B + (size_t)(bn + srow) * Kstride + clocal;
  const _Float16* pB1 = B + (size_t)(bn + 128 + srow) * Kstride + clocal;

  _Float16* const dA0 = lds + w * 1024;
  _Float16* const dA1 = lds + 8192 + w * 1024;
  _Float16* const dB0 = lds + 16384 + w * 1024;
  _Float16* const dB1 = lds + 24576 + w * 1024;

  const int aH = w >> 2, bH = (w >> 1) & 1, bRB = (w & 1) * 4;
  const _Float16* const rA0 = lds + aH * 8192;
  const _Float16* const rB0 = lds + 16384 + bH * 8192;
  const _Float16* const rA1 = rA0 + 32768;
  const _Float16* const rB1 = rB0 + 32768;

  const int NT = Kloop >> 6;  // 64-wide K tiles (always even here)

#define STG(p, d, kt)                     \
  do {                                    \
    const _Float16* _s = (p) + (kt) * 64; \
    load_lds16(_s, (d));                  \
    load_lds16(_s + 32, (d) + 512);       \
  } while (0)
#define BARRIER() asm volatile("s_barrier" ::: "memory")
#define WAIT_LGKM()                                  \
  asm volatile("s_waitcnt lgkmcnt(0)" ::: "memory"); \
  __builtin_amdgcn_sched_barrier(0);
#define RD_A(base, RB0)                                                       \
  _Pragma("unroll") for (int rb = 0; rb < 4; rb++)                            \
  _Pragma("unroll") for (int ks = 0; ks < 2; ks++)                            \
      af[rb][ks] = *(const half8*)&(base)[((((RB0) + rb) * 2 + ks) << 9) + rdh];
#define RD_B(base, J0)                                                        \
  _Pragma("unroll") for (int j = 0; j < 2; j++)                               \
  _Pragma("unroll") for (int ks = 0; ks < 2; ks++)                            \
      bf[(J0) + j][ks] =                                                      \
          *(const half8*)&(base)[(((bRB + (J0) + j) * 2 + ks) << 9) + rdh];
#define MFMA_Q(RB0, J0)                                                       \
  __builtin_amdgcn_s_setprio(1);                                              \
  _Pragma("unroll") for (int rb = 0; rb < 4; rb++)                            \
  _Pragma("unroll") for (int j = 0; j < 2; j++)                               \
  _Pragma("unroll") for (int ks = 0; ks < 2; ks++)                            \
      acc[(RB0) + rb][(J0) + j] = __builtin_amdgcn_mfma_f32_16x16x32_f16(     \
          af[rb][ks], bf[(J0) + j][ks], acc[(RB0) + rb][(J0) + j], 0, 0, 0);  \
  __builtin_amdgcn_s_setprio(0);                                              \
  BARRIER();

  // prologue: tile0 {B0,B1,A0,A1} + tile1 {B0,B1}; retire tile0 (8 instr)
  STG(pB0, dB0, 0); STG(pB1, dB1, 0); STG(pA0, dA0, 0); STG(pA1, dA1, 0);
  STG(pB0, dB0 + 32768, 1); STG(pB1, dB1 + 32768, 1);
  asm volatile("s_waitcnt vmcnt(4)" ::: "memory");
  BARRIER();

  half8 af[4][2], bf[4][2];

  for (int t = 0; t < NT; t += 2) {
    const bool last = (t + 2 >= NT);
    // ---- tile t (buf0) ----
    RD_A(rA0, 0) RD_B(rB0, 0)
    STG(pA0, dA0 + 32768, t + 1);
    BARRIER(); WAIT_LGKM()
    MFMA_Q(0, 0)
    RD_B(rB0, 2)
    STG(pA1, dA1 + 32768, t + 1);
    BARRIER(); WAIT_LGKM()
    MFMA_Q(0, 2)
    RD_A(rA0, 4)
    if (!last) STG(pB0, dB0, t + 2);
    BARRIER(); WAIT_LGKM()
    MFMA_Q(4, 0)
    if (!last) {
      STG(pA0, dA0, t + 2);
      asm volatile("s_waitcnt vmcnt(4)" ::: "memory");
    } else {
      asm volatile("s_waitcnt vmcnt(0)" ::: "memory");
    }
    BARRIER();
    MFMA_Q(4, 2)
    // ---- tile t+1 (buf1) ----
    RD_A(rA1, 0) RD_B(rB1, 0)
    if (!last) STG(pA1, dA1, t + 2);
    BARRIER(); WAIT_LGKM()
    MFMA_Q(0, 0)
    RD_B(rB1, 2)
    if (!last) STG(pB1, dB1, t + 2);
    BARRIER(); WAIT_LGKM()
    MFMA_Q(0, 2)
    RD_A(rA1, 4)
    if (!last) STG(pB0, dB0 + 32768, t + 3);
    BARRIER(); WAIT_LGKM()
    MFMA_Q(4, 0)
    if (!last) {
      STG(pB1, dB1 + 32768, t + 3);
      asm volatile("s_waitcnt vmcnt(4)" ::: "memory");
    }
    BARRIER();
    MFMA_Q(4, 2)
  }
#undef STG
#undef BARRIER
#undef WAIT_LGKM
#undef RD_A
#undef RD_B
#undef MFMA_Q
}

// ---------------- QKV: one launch, z = 0(Q)/1(K)/2(V transposed) ---------
__global__ __launch_bounds__(512, 2) void gemm_qkv(
    const _Float16* __restrict__ xh, const _Float16* __restrict__ Wq,
    const _Float16* __restrict__ Wk, const _Float16* __restrict__ Wv,
    _Float16* __restrict__ Qh, _Float16* __restrict__ Kh,
    _Float16* __restrict__ Vt) {
  __shared__ __align__(16) _Float16 lds[67584];  // 132 KiB (V-Tr needs 256*264)
  const int z = blockIdx.z;
  const _Float16* B = (z == 0) ? Wq : (z == 1 ? Wk : Wv);
  const int bm = blockIdx.y * 256, bn = blockIdx.x * 256;
  float4v acc[8][4] = {};
  gemm8_core(xh, B, 2048, 2048, bm, bn, lds, acc);

  const int tid = threadIdx.x;
  const int w = tid >> 6, lane = tid & 63;
  const int l16 = lane & 15, quad = lane >> 4;
  const int wm = (w >> 2) * 128, wn = (w & 3) * 64;
  if (z == 2) {
    // V: transpose through LDS -> coalesced 16B column-major stores.
    _Float16* Tr = lds;  // [col][m], stride 264 halves
    __syncthreads();
#pragma unroll
    for (int j = 0; j < 4; j++) {
      const int cl = wn + j * 16 + l16;
#pragma unroll
      for (int rb = 0; rb < 8; rb++) {
        const int ml = wm + rb * 16 + quad * 4;
#pragma unroll
        for (int reg = 0; reg < 4; reg++)
          Tr[cl * 264 + ml + reg] = (_Float16)acc[rb][j][reg];
      }
    }
    __syncthreads();
    const int cl = tid >> 1;
    const int ml = (tid & 1) * 128;
    const int mg = bm + ml;
    _Float16* dst = Vt + ((size_t)(mg >> 11) << 22) +
                    ((size_t)(bn + cl) << 11) + (mg & 2047);
#pragma unroll
    for (int i = 0; i < 16; i++)
      *(half8*)(dst + i * 8) = *(const half8*)&Tr[cl * 264 + ml + i * 8];
  } else {
    _Float16* outRM = z ? Kh : Qh;
#pragma unroll
    for (int j = 0; j < 4; j++) {
      const int col = bn + wn + j * 16 + l16;
#pragma unroll
      for (int rb = 0; rb < 8; rb++) {
        const int rbase = bm + wm + rb * 16 + quad * 4;
#pragma unroll
        for (int reg = 0; reg < 4; reg++)
          outRM[(size_t)(rbase + reg) * 2048 + col] = (_Float16)acc[rb][j][reg];
      }
    }
  }
}

// ---------------- FFN1 GEMM (GELU sigmoid-form, f16 out, direct) ---------
__global__ __launch_bounds__(512, 2) void gemm_ffn1(
    const _Float16* __restrict__ A, const _Float16* __restrict__ B,
    const float* __restrict__ bias, _Float16* __restrict__ out, int N, int K) {
  __shared__ __align__(16) _Float16 lds[65536];
  const int bm = blockIdx.y * 256, bn = blockIdx.x * 256;
  float4v acc[8][4] = {};
  gemm8_core(A, B, K, K, bm, bn, lds, acc);

  const int tid = threadIdx.x;
  const int w = tid >> 6, lane = tid & 63;
  const int l16 = lane & 15, quad = lane >> 4;
  const int wm = (w >> 2) * 128, wn = (w & 3) * 64;
#pragma unroll
  for (int j = 0; j < 4; j++) {
    const int col = bn + wn + j * 16 + l16;
    const float bv = bias[col];
#pragma unroll
    for (int rb = 0; rb < 8; rb++) {
      const int rbase = bm + wm + rb * 16 + quad * 4;
#pragma unroll
      for (int reg = 0; reg < 4; reg++) {
        const int m = rbase + reg;
        const float x = acc[rb][j][reg] + bv;
        const float t = x + 0.044715f * x * x * x;
        const float e = exp2f(-2.302208198f * t);  // exp(-1.59576912*t)
        out[(size_t)m * N + col] = (_Float16)(x / (1.0f + e));
      }
    }
  }
}

// ---------------- FFN2 split-K partial GEMM (f32 out, no bias) -----------
__global__ __launch_bounds__(512, 2) void gemm_ffn2_part(
    const _Float16* __restrict__ A, const _Float16* __restrict__ B,
    float* __restrict__ p0, float* __restrict__ p1) {
  __shared__ __align__(16) _Float16 lds[65536];
  const int bm = blockIdx.y * 256, bn = blockIdx.x * 256;
  const int k0 = blockIdx.z * 2048;
  float* out = blockIdx.z ? p1 : p0;
  float4v acc[8][4] = {};
  gemm8_core(A + k0, B + k0, 2048, 4096, bm, bn, lds, acc);

  const int tid = threadIdx.x;
  const int w = tid >> 6, lane = tid & 63;
  const int l16 = lane & 15, quad = lane >> 4;
  const int wm = (w >> 2) * 128, wn = (w & 3) * 64;
#pragma unroll
  for (int j = 0; j < 4; j++) {
    const int col = bn + wn + j * 16 + l16;
#pragma unroll
    for (int rb = 0; rb < 8; rb++) {
      const int rbase = bm + wm + rb * 16 + quad * 4;
#pragma unroll
      for (int reg = 0; reg < 4; reg++)
        out[(size_t)(rbase + reg) * 2048 + col] = acc[rb][j][reg];
    }
  }
}

// ---------------- split-K reduce: out += p0 + bias -----------------------
__global__ void reduce_add(float* __restrict__ out, const float* __restrict__ p0,
                           const float* __restrict__ b2, int n) {
  const int step = gridDim.x * 256 * 4;
  for (int i = (blockIdx.x * 256 + threadIdx.x) * 4; i < n; i += step) {
    float4v a = *(const float4v*)&out[i];
    float4v b = *(const float4v*)&p0[i];
    float4v bb = *(const float4v*)&b2[i & 2047];
    float4v r;
#pragma unroll
    for (int e = 0; e < 4; e++) r[e] = a[e] + b[e] + bb[e];
    *(float4v*)&out[i] = r;
  }
}

// ---------------- fp16 MFMA flash attention (KVBLK=64, XOR-swizzled LDS) -
// One block per (b, h, 128-row q-tile); 4 waves x 32 q-rows. Flat LDS:
// Ksh[key:64][d:128], Vsh[d:128][key:64], Psh[w][qrow:32][key:64] with
// col ^ ((row&7)<<3) swizzle on write AND read (bijective per row, 16B
// aligned) -> ~2-way banks. 48 KB LDS -> 3 blocks/CU. Shuffle max-tree
// only on rescale tiles; rowsum via mfma(P,ones); O via Ksh transpose.
__global__ __launch_bounds__(256, 3) void attn_mfma(
    const _Float16* __restrict__ Qh, const _Float16* __restrict__ Kh,
    const _Float16* __restrict__ Vt, _Float16* __restrict__ Oh) {
  __shared__ __align__(16) _Float16 Ksh[8192];    // [64][128] swz; O-Tr after
  __shared__ __align__(16) _Float16 Vsh[8192];    // [128][64] swz
  __shared__ __align__(16) _Float16 Psh[4][2048]; // per-wave [32][64] swz

  const int b = blockIdx.z;
  int qt = blockIdx.x;
  if (b) qt = gridDim.x - 1 - qt;  // heavy/light pairing across CUs
  const int h = blockIdx.y;
  const int tid = threadIdx.x;
  const int wave = tid >> 6, lane = tid & 63;
  const int l16 = lane & 15, quad = lane >> 4;
  const int q0 = qt * 128;
  const int wq0 = q0 + wave * 32;
  const int rxor = (l16 & 7) << 3;  // b128 read swizzle (row low bits = l16)

  half8 qf[2][4];
#pragma unroll
  for (int rb = 0; rb < 2; rb++)
#pragma unroll
    for (int kc = 0; kc < 4; kc++)
      qf[rb][kc] = *(const half8*)(Qh +
          (size_t)(b * 2048 + wq0 + rb * 16 + l16) * 2048 + h * 128 +
          kc * 32 + quad * 8);

  half8 ones;
#pragma unroll
  for (int e = 0; e < 8; e++) ones[e] = (_Float16)1.0f;

  const int kkey = tid >> 2, kd = (tid & 3) * 32;
  const int vd = tid >> 1, vkey = (tid & 1) * 32;
  const int kswz = (kkey & 7) << 3;
  const int vswz = (vd & 7) << 3;

  half8 kpre[4], vpre[4];
  {
    const _Float16* p = Kh + (size_t)(b * 2048 + kkey) * 2048 + h * 128 + kd;
#pragma unroll
    for (int i = 0; i < 4; i++) kpre[i] = *(const half8*)(p + i * 8);
    const _Float16* pv = Vt + ((size_t)b << 22) + (size_t)(h * 128 + vd) * 2048 + vkey;
#pragma unroll
    for (int i = 0; i < 4; i++) vpre[i] = *(const half8*)(pv + i * 8);
  }

  float4v o[2][9] = {};  // [rb][0..7]=O cols, [8]=row-sum accumulator
  float4v mrow[2];
#pragma unroll
  for (int rb = 0; rb < 2; rb++)
#pragma unroll
    for (int e = 0; e < 4; e++) mrow[rb][e] = -INFINITY;

  const int nkb = qt * 2 + 2;  // 64-key tiles
  for (int kb = 0; kb < nkb; kb++) {
    const int k0 = kb * 64;
    __syncthreads();
#pragma unroll
    for (int i = 0; i < 4; i++)
      *(half8*)&Ksh[kkey * 128 + ((kd + i * 8) ^ kswz)] = kpre[i];
#pragma unroll
    for (int i = 0; i < 4; i++)
      *(half8*)&Vsh[vd * 64 + ((vkey + i * 8) ^ vswz)] = vpre[i];
    __syncthreads();

    if (kb + 1 < nkb) {
      const int k1 = k0 + 64;
      const _Float16* p = Kh + (size_t)(b * 2048 + k1 + kkey) * 2048 + h * 128 + kd;
#pragma unroll
      for (int i = 0; i < 4; i++) kpre[i] = *(const half8*)(p + i * 8);
      const _Float16* pv = Vt + ((size_t)b << 22) + (size_t)(h * 128 + vd) * 2048 + k1 + vkey;
#pragma unroll
      for (int i = 0; i < 4; i++) vpre[i] = *(const half8*)(pv + i * 8);
    }

    if (k0 <= wq0 + 31) {
      float4v s[2][4] = {};
#pragma unroll
      for (int kc = 0; kc < 4; kc++) {
#pragma unroll
        for (int cb = 0; cb < 4; cb++) {
          half8 kf = *(const half8*)&Ksh[(cb * 16 + l16) * 128 +
                                         ((kc * 32 + quad * 8) ^ rxor)];
#pragma unroll
          for (int rb = 0; rb < 2; rb++)
            s[rb][cb] = __builtin_amdgcn_mfma_f32_16x16x32_f16(qf[rb][kc], kf, s[rb][cb], 0, 0, 0);
        }
      }
      if (k0 + 63 > wq0) {
#pragma unroll
        for (int cb = 0; cb < 4; cb++)
#pragma unroll
          for (int rb = 0; rb < 2; rb++)
#pragma unroll
            for (int reg = 0; reg < 4; reg++) {
              const int key = k0 + cb * 16 + l16;
              const int row = wq0 + rb * 16 + quad * 4 + reg;
              if (key > row) s[rb][cb][reg] = -INFINITY;
            }
      }
#pragma unroll
      for (int rb = 0; rb < 2; rb++) {
        float4v mt;
#pragma unroll
        for (int e = 0; e < 4; e++)
          mt[e] = fmaxf(fmaxf(s[rb][0][e], s[rb][1][e]),
                        fmaxf(s[rb][2][e], s[rb][3][e]));
        int need = 0;
#pragma unroll
        for (int e = 0; e < 4; e++) need |= (mt[e] > mrow[rb][e] + 8.0f) ? 1 : 0;
        if (__any(need)) {  // rare: full row-reduce + rescale only here
#pragma unroll
          for (int msk = 1; msk <= 8; msk <<= 1)
#pragma unroll
            for (int e = 0; e < 4; e++) mt[e] = fmaxf(mt[e], __shfl_xor(mt[e], msk, 64));
          float4v al;
#pragma unroll
          for (int e = 0; e < 4; e++) {
            const float mn = fmaxf(mrow[rb][e], mt[e]);
            al[e] = exp2f(mrow[rb][e] - mn);
            mrow[rb][e] = mn;
          }
#pragma unroll
          for (int cd = 0; cd < 9; cd++)
#pragma unroll
            for (int e = 0; e < 4; e++) o[rb][cd][e] *= al[e];
        }
#pragma unroll
        for (int cb = 0; cb < 4; cb++) {
#pragma unroll
          for (int e = 0; e < 4; e++) s[rb][cb][e] = exp2f(s[rb][cb][e] - mrow[rb][e]);
#pragma unroll
          for (int e = 0; e < 4; e++) {
            const int pr = rb * 16 + quad * 4 + e;
            Psh[wave][pr * 64 + ((cb * 16 + l16) ^ ((pr & 7) << 3))] =
                (_Float16)s[rb][cb][e];
          }
        }
      }
      half8 pf[2][2];
#pragma unroll
      for (int rb = 0; rb < 2; rb++)
#pragma unroll
        for (int kc = 0; kc < 2; kc++)
          pf[rb][kc] = *(const half8*)&Psh[wave][(rb * 16 + l16) * 64 +
                                                 ((kc * 32 + quad * 8) ^ rxor)];
#pragma unroll
      for (int cd = 0; cd < 8; cd++) {
#pragma unroll
        for (int kc = 0; kc < 2; kc++) {
          half8 vf = *(const half8*)&Vsh[(cd * 16 + l16) * 64 +
                                         ((kc * 32 + quad * 8) ^ rxor)];
#pragma unroll
          for (int rb = 0; rb < 2; rb++)
            o[rb][cd] = __builtin_amdgcn_mfma_f32_16x16x32_f16(pf[rb][kc], vf, o[rb][cd], 0, 0, 0);
        }
      }
#pragma unroll
      for (int kc = 0; kc < 2; kc++)
#pragma unroll
        for (int rb = 0; rb < 2; rb++)
          o[rb][8] = __builtin_amdgcn_mfma_f32_16x16x32_f16(pf[rb][kc], ones, o[rb][8], 0, 0, 0);
    }
  }

  // ---- finalize: O /= rowsum, via Ksh transpose -> coalesced stores ----
  float4v inv[2];
#pragma unroll
  for (int rb = 0; rb < 2; rb++)
#pragma unroll
    for (int e = 0; e < 4; e++) inv[rb][e] = 1.0f / o[rb][8][e];

#pragma unroll 1
  for (int p = 0; p < 2; p++) {  // waves {2p,2p+1} -> q rows q0+p*64..+63
    __syncthreads();
    if ((wave >> 1) == p) {
      _Float16* slab = &Ksh[(wave & 1) * 32 * 128];  // rows 0..63 of 64x128
#pragma unroll
      for (int rb = 0; rb < 2; rb++)
#pragma unroll
        for (int cd = 0; cd < 8; cd++)
#pragma unroll
          for (int reg = 0; reg < 4; reg++) {
            const int rr = rb * 16 + quad * 4 + reg;
            slab[rr * 128 + ((cd * 16 + l16) ^ ((rr & 7) << 3))] =
                (_Float16)(o[rb][cd][reg] * inv[rb][reg]);
          }
    }
    __syncthreads();
    const int r = tid >> 2, c = (tid & 3) * 8;  // 64 rows x 128 cols
    const int oxor = (r & 7) << 3;
    _Float16* dst = Oh + (size_t)(b * 2048 + q0 + p * 64 + r) * 2048 + h * 128 + c;
#pragma unroll
    for (int i = 0; i < 4; i++)
      *(half8*)(dst + i * 32) = *(const half8*)&Ksh[r * 128 + ((c + i * 32) ^ oxor)];
  }
}

// ---------------- launcher ----------------------------------------------
extern "C" void kernel_launch(void* const* d_in, const int* in_sizes, int n_in,
                              void* d_out, int out_size, void* d_ws,
                              size_t ws_size, hipStream_t stream) {
  const float* x = (const float*)d_in[0];
  const float* Wq = (const float*)d_in[1];
  const float* Wk = (const float*)d_in[2];
  const float* Wv = (const float*)d_in[3];
  const float* W1 = (const float*)d_in[4];
  const float* b1 = (const float*)d_in[5];
  const float* W2 = (const float*)d_in[6];
  const float* b2 = (const float*)d_in[7];
  float* out = (float*)d_out;

  const int ME = 8388608;  // 4096*2048 (also numel(x))
  const int EE = 4194304;  // 2048*2048

  _Float16* ws = (_Float16*)d_ws;
  _Float16* xh  = ws;                 // 8.4M halves
  _Float16* Wqh = xh + ME;            // 4.2M
  _Float16* Wkh = Wqh + EE;
  _Float16* Wvh = Wkh + EE;
  _Float16* Qh  = Wvh + EE;           // 8.4M
  _Float16* Kh  = Qh + ME;
  _Float16* Vt  = Kh + ME;            // ends at 92.3 MB
  _Float16* Oh  = xh;                 // alias (xh dead after QKV)
  _Float16* W1h = Wqh;                // alias over Wq+Wk (dead after QKV)
  _Float16* W2h = Vt;                 // alias (Vt dead after attention)
  _Float16* Hid = Qh;                 // alias over Qh+Kh (dead after attention)
  float*    P0  = (float*)ws;         // ffn2 f32 partial (xh span, dead then)

  const float qscale = 1.4426950408889634f * 0.08838834764831845f;  // log2e/sqrt(128)

  // convert x (and fold qscale into Wq), Wk, Wv
  cvt_kernel<<<dim3(1024, 4), 256, 0, stream>>>(x, Wq, Wk, Wv, xh, Wqh, Wkh, Wvh,
                                                ME, EE, EE, EE, qscale);
  // QKV projections: one launch, z = 0/1/2  (256x256 tiles)
  gemm_qkv<<<dim3(8, 16, 3), 512, 0, stream>>>(xh, Wqh, Wkh, Wvh, Qh, Kh, Vt);
  // attention: 512 blocks, 256 threads, 3 blocks/CU
  attn_mfma<<<dim3(16, 16, 2), 256, 0, stream>>>(Qh, Kh, Vt, Oh);
  // convert FFN weights (regions now dead)
  cvt_kernel<<<dim3(1024, 2), 256, 0, stream>>>(W1, W2, nullptr, nullptr,
                                                W1h, W2h, nullptr, nullptr,
                                                ME, ME, 0, 0, 1.0f);
  // FFN1
  gemm_ffn1<<<dim3(16, 16), 512, 0, stream>>>(Oh, W1h, b1, Hid, 4096, 2048);
  // FFN2: split-K x2 (256 blocks, full machine) + reduce with bias
  gemm_ffn2_part<<<dim3(8, 16, 2), 512, 0, stream>>>(Hid, W2h, P0, out);
  reduce_add<<<dim3(2048), 256, 0, stream>>>(out, P0, b2, ME);
}

// Round 9
// 540.323 us; speedup vs baseline: 1.4459x; 1.4459x over previous
//
#include <hip/hip_runtime.h>
#include <cmath>

// B=2, S=2048, E=2048, H=16, D=128, M=B*S=4096, F=2E=4096
// Round-9 = full revert to the round-4 kernel (best passing, 547us):
// m201 8-phase 256x256 GEMM core, direct-store epilogues, V via LDS
// transpose, split-K ffn2 + reduce. Attention is the R4 version
// (KVBLK=64, padded LDS strides, 2 blocks/CU) — R7's big-tile and R8's
// swizzle+3/CU variants both regressed (R8: L2 thrash, FETCH 85->336MB).
// Only two verified-safe micro-deltas kept: rare-path shuffle max-tree
// and sigmoid-form GELU.

typedef _Float16 half8 __attribute__((ext_vector_type(8)));
typedef _Float16 half4v __attribute__((ext_vector_type(4)));
typedef float float4v __attribute__((ext_vector_type(4)));

__device__ inline void load_lds16(const _Float16* g, _Float16* l) {
  __builtin_amdgcn_global_load_lds(
      (const __attribute__((address_space(1))) void*)g,
      (__attribute__((address_space(3))) void*)l, 16, 0, 0);
}

// ---------------- fp32 -> fp16 convert (up to 4 arrays per launch) -------
__global__ void cvt_kernel(const float* __restrict__ s0, const float* __restrict__ s1,
                           const float* __restrict__ s2, const float* __restrict__ s3,
                           _Float16* d0, _Float16* d1, _Float16* d2, _Float16* d3,
                           int n0, int n1, int n2, int n3, float sc1) {
  const float* s;
  _Float16* d;
  int n;
  float sc = 1.0f;
  switch (blockIdx.y) {
    case 0: s = s0; d = d0; n = n0; break;
    case 1: s = s1; d = d1; n = n1; sc = sc1; break;
    case 2: s = s2; d = d2; n = n2; break;
    default: s = s3; d = d3; n = n3; break;
  }
  const int step = gridDim.x * 256 * 4;
  for (int i = (blockIdx.x * 256 + threadIdx.x) * 4; i < n; i += step) {
    float4v v = *(const float4v*)&s[i];
    half4v h;
#pragma unroll
    for (int e = 0; e < 4; e++) h[e] = (_Float16)(v[e] * sc);
    *(half4v*)&d[i] = h;
  }
}

// ---------------- 8-phase 256x256 GEMM core (round-2 schedule) -----------
__device__ __forceinline__ void gemm8_core(
    const _Float16* __restrict__ A, const _Float16* __restrict__ B, int Kloop,
    int Kstride, int bm, int bn, _Float16* lds, float4v acc[8][4]) {
  const int tid = threadIdx.x;
  const int w = tid >> 6, lane = tid & 63;
  const int l16 = lane & 15, quad = lane >> 4;
  const int srow = w * 16 + (lane >> 2);
  const int clocal = ((lane & 3) * 8) ^ ((lane & 32) ? 16 : 0);
  int rdh = (l16 << 5) + (quad << 3);
  rdh ^= (l16 & 8) << 1;  // st_16x32: ^32B when row&8

  const _Float16* pA0 = A + (size_t)(bm + srow) * Kstride + clocal;
  const _Float16* pA1 = A + (size_t)(bm + 128 + srow) * Kstride + clocal;
  const _Float16* pB0 = B + (size_t)(bn + srow) * Kstride + clocal;
  const _Float16* pB1 = B + (size_t)(bn + 128 + srow) * Kstride + clocal;

  _Float16* const dA0 = lds + w * 1024;
  _Float16* const dA1 = lds + 8192 + w * 1024;
  _Float16* const dB0 = lds + 16384 + w * 1024;
  _Float16* const dB1 = lds + 24576 + w * 1024;

  const int aH = w >> 2, bH = (w >> 1) & 1, bRB = (w & 1) * 4;
  const _Float16* const rA0 = lds + aH * 8192;
  const _Float16* const rB0 = lds + 16384 + bH * 8192;
  const _Float16* const rA1 = rA0 + 32768;
  const _Float16* const rB1 = rB0 + 32768;

  const int NT = Kloop >> 6;  // 64-wide K tiles (always even here)

#define STG(p, d, kt)                     \
  do {                                    \
    const _Float16* _s = (p) + (kt) * 64; \
    load_lds16(_s, (d));                  \
    load_lds16(_s + 32, (d) + 512);       \
  } while (0)
#define BARRIER() asm volatile("s_barrier" ::: "memory")
#define WAIT_LGKM()                                  \
  asm volatile("s_waitcnt lgkmcnt(0)" ::: "memory"); \
  __builtin_amdgcn_sched_barrier(0);
#define RD_A(base, RB0)                                                       \
  _Pragma("unroll") for (int rb = 0; rb < 4; rb++)                            \
  _Pragma("unroll") for (int ks = 0; ks < 2; ks++)                            \
      af[rb][ks] = *(const half8*)&(base)[((((RB0) + rb) * 2 + ks) << 9) + rdh];
#define RD_B(base, J0)                                                        \
  _Pragma("unroll") for (int j = 0; j < 2; j++)                               \
  _Pragma("unroll") for (int ks = 0; ks < 2; ks++)                            \
      bf[(J0) + j][ks] =                                                      \
          *(const half8*)&(base)[(((bRB + (J0) + j) * 2 + ks) << 9) + rdh];
#define MFMA_Q(RB0, J0)                                                       \
  __builtin_amdgcn_s_setprio(1);                                              \
  _Pragma("unroll") for (int rb = 0; rb < 4; rb++)                            \
  _Pragma("unroll") for (int j = 0; j < 2; j++)                               \
  _Pragma("unroll") for (int ks = 0; ks < 2; ks++)                            \
      acc[(RB0) + rb][(J0) + j] = __builtin_amdgcn_mfma_f32_16x16x32_f16(     \
          af[rb][ks], bf[(J0) + j][ks], acc[(RB0) + rb][(J0) + j], 0, 0, 0);  \
  __builtin_amdgcn_s_setprio(0);                                              \
  BARRIER();

  // prologue: tile0 {B0,B1,A0,A1} + tile1 {B0,B1}; retire tile0 (8 instr)
  STG(pB0, dB0, 0); STG(pB1, dB1, 0); STG(pA0, dA0, 0); STG(pA1, dA1, 0);
  STG(pB0, dB0 + 32768, 1); STG(pB1, dB1 + 32768, 1);
  asm volatile("s_waitcnt vmcnt(4)" ::: "memory");
  BARRIER();

  half8 af[4][2], bf[4][2];

  for (int t = 0; t < NT; t += 2) {
    const bool last = (t + 2 >= NT);
    // ---- tile t (buf0) ----
    RD_A(rA0, 0) RD_B(rB0, 0)
    STG(pA0, dA0 + 32768, t + 1);
    BARRIER(); WAIT_LGKM()
    MFMA_Q(0, 0)
    RD_B(rB0, 2)
    STG(pA1, dA1 + 32768, t + 1);
    BARRIER(); WAIT_LGKM()
    MFMA_Q(0, 2)
    RD_A(rA0, 4)
    if (!last) STG(pB0, dB0, t + 2);
    BARRIER(); WAIT_LGKM()
    MFMA_Q(4, 0)
    if (!last) {
      STG(pA0, dA0, t + 2);
      asm volatile("s_waitcnt vmcnt(4)" ::: "memory");
    } else {
      asm volatile("s_waitcnt vmcnt(0)" ::: "memory");
    }
    BARRIER();
    MFMA_Q(4, 2)
    // ---- tile t+1 (buf1) ----
    RD_A(rA1, 0) RD_B(rB1, 0)
    if (!last) STG(pA1, dA1, t + 2);
    BARRIER(); WAIT_LGKM()
    MFMA_Q(0, 0)
    RD_B(rB1, 2)
    if (!last) STG(pB1, dB1, t + 2);
    BARRIER(); WAIT_LGKM()
    MFMA_Q(0, 2)
    RD_A(rA1, 4)
    if (!last) STG(pB0, dB0 + 32768, t + 3);
    BARRIER(); WAIT_LGKM()
    MFMA_Q(4, 0)
    if (!last) {
      STG(pB1, dB1 + 32768, t + 3);
      asm volatile("s_waitcnt vmcnt(4)" ::: "memory");
    }
    BARRIER();
    MFMA_Q(4, 2)
  }
#undef STG
#undef BARRIER
#undef WAIT_LGKM
#undef RD_A
#undef RD_B
#undef MFMA_Q
}

// ---------------- QKV: one launch, z = 0(Q)/1(K)/2(V transposed) ---------
__global__ __launch_bounds__(512, 2) void gemm_qkv(
    const _Float16* __restrict__ xh, const _Float16* __restrict__ Wq,
    const _Float16* __restrict__ Wk, const _Float16* __restrict__ Wv,
    _Float16* __restrict__ Qh, _Float16* __restrict__ Kh,
    _Float16* __restrict__ Vt) {
  __shared__ __align__(16) _Float16 lds[67584];  // 132 KiB (V-Tr needs 256*264)
  const int z = blockIdx.z;
  const _Float16* B = (z == 0) ? Wq : (z == 1 ? Wk : Wv);
  const int bm = blockIdx.y * 256, bn = blockIdx.x * 256;
  float4v acc[8][4] = {};
  gemm8_core(xh, B, 2048, 2048, bm, bn, lds, acc);

  const int tid = threadIdx.x;
  const int w = tid >> 6, lane = tid & 63;
  const int l16 = lane & 15, quad = lane >> 4;
  const int wm = (w >> 2) * 128, wn = (w & 3) * 64;
  if (z == 2) {
    // V: transpose through LDS -> coalesced 16B column-major stores.
    _Float16* Tr = lds;  // [col][m], stride 264 halves
    __syncthreads();
#pragma unroll
    for (int j = 0; j < 4; j++) {
      const int cl = wn + j * 16 + l16;
#pragma unroll
      for (int rb = 0; rb < 8; rb++) {
        const int ml = wm + rb * 16 + quad * 4;
#pragma unroll
        for (int reg = 0; reg < 4; reg++)
          Tr[cl * 264 + ml + reg] = (_Float16)acc[rb][j][reg];
      }
    }
    __syncthreads();
    const int cl = tid >> 1;
    const int ml = (tid & 1) * 128;
    const int mg = bm + ml;
    _Float16* dst = Vt + ((size_t)(mg >> 11) << 22) +
                    ((size_t)(bn + cl) << 11) + (mg & 2047);
#pragma unroll
    for (int i = 0; i < 16; i++)
      *(half8*)(dst + i * 8) = *(const half8*)&Tr[cl * 264 + ml + i * 8];
  } else {
    _Float16* outRM = z ? Kh : Qh;
#pragma unroll
    for (int j = 0; j < 4; j++) {
      const int col = bn + wn + j * 16 + l16;
#pragma unroll
      for (int rb = 0; rb < 8; rb++) {
        const int rbase = bm + wm + rb * 16 + quad * 4;
#pragma unroll
        for (int reg = 0; reg < 4; reg++)
          outRM[(size_t)(rbase + reg) * 2048 + col] = (_Float16)acc[rb][j][reg];
      }
    }
  }
}

// ---------------- FFN1 GEMM (GELU sigmoid-form, f16 out, direct) ---------
__global__ __launch_bounds__(512, 2) void gemm_ffn1(
    const _Float16* __restrict__ A, const _Float16* __restrict__ B,
    const float* __restrict__ bias, _Float16* __restrict__ out, int N, int K) {
  __shared__ __align__(16) _Float16 lds[65536];
  const int bm = blockIdx.y * 256, bn = blockIdx.x * 256;
  float4v acc[8][4] = {};
  gemm8_core(A, B, K, K, bm, bn, lds, acc);

  const int tid = threadIdx.x;
  const int w = tid >> 6, lane = tid & 63;
  const int l16 = lane & 15, quad = lane >> 4;
  const int wm = (w >> 2) * 128, wn = (w & 3) * 64;
#pragma unroll
  for (int j = 0; j < 4; j++) {
    const int col = bn + wn + j * 16 + l16;
    const float bv = bias[col];
#pragma unroll
    for (int rb = 0; rb < 8; rb++) {
      const int rbase = bm + wm + rb * 16 + quad * 4;
#pragma unroll
      for (int reg = 0; reg < 4; reg++) {
        const int m = rbase + reg;
        const float x = acc[rb][j][reg] + bv;
        const float t = x + 0.044715f * x * x * x;
        const float e = exp2f(-2.302208198f * t);  // exp(-1.59576912*t)
        out[(size_t)m * N + col] = (_Float16)(x / (1.0f + e));
      }
    }
  }
}

// ---------------- FFN2 split-K partial GEMM (f32 out, no bias) -----------
__global__ __launch_bounds__(512, 2) void gemm_ffn2_part(
    const _Float16* __restrict__ A, const _Float16* __restrict__ B,
    float* __restrict__ p0, float* __restrict__ p1) {
  __shared__ __align__(16) _Float16 lds[65536];
  const int bm = blockIdx.y * 256, bn = blockIdx.x * 256;
  const int k0 = blockIdx.z * 2048;
  float* out = blockIdx.z ? p1 : p0;
  float4v acc[8][4] = {};
  gemm8_core(A + k0, B + k0, 2048, 4096, bm, bn, lds, acc);

  const int tid = threadIdx.x;
  const int w = tid >> 6, lane = tid & 63;
  const int l16 = lane & 15, quad = lane >> 4;
  const int wm = (w >> 2) * 128, wn = (w & 3) * 64;
#pragma unroll
  for (int j = 0; j < 4; j++) {
    const int col = bn + wn + j * 16 + l16;
#pragma unroll
    for (int rb = 0; rb < 8; rb++) {
      const int rbase = bm + wm + rb * 16 + quad * 4;
#pragma unroll
      for (int reg = 0; reg < 4; reg++)
        out[(size_t)(rbase + reg) * 2048 + col] = acc[rb][j][reg];
    }
  }
}

// ---------------- split-K reduce: out += p0 + bias -----------------------
__global__ void reduce_add(float* __restrict__ out, const float* __restrict__ p0,
                           const float* __restrict__ b2, int n) {
  const int step = gridDim.x * 256 * 4;
  for (int i = (blockIdx.x * 256 + threadIdx.x) * 4; i < n; i += step) {
    float4v a = *(const float4v*)&out[i];
    float4v b = *(const float4v*)&p0[i];
    float4v bb = *(const float4v*)&b2[i & 2047];
    float4v r;
#pragma unroll
    for (int e = 0; e < 4; e++) r[e] = a[e] + b[e] + bb[e];
    *(float4v*)&out[i] = r;
  }
}

// ---------------- fp16 MFMA flash attention (R4 structure) ---------------
// One block per (b, h, 128-row q-tile); 4 waves x 32 q-rows; KVBLK=64;
// padded LDS strides (2-way-free banks); 2 blocks/CU (R8 showed 3/CU
// destroys L2 K/V reuse: FETCH 85->336MB). Qh pre-scaled by log2e/sqrt(D).
// Rowsum via mfma(P, ones); deferred rescale (THR=8): shuffle max-tree
// runs only on rescale tiles (trigger equivalent wave-wide).
__global__ __launch_bounds__(256, 2) void attn_mfma(
    const _Float16* __restrict__ Qh, const _Float16* __restrict__ Kh,
    const _Float16* __restrict__ Vt, _Float16* __restrict__ Oh) {
  __shared__ __align__(16) _Float16 Ksh[64][136];   // [key][d]
  __shared__ __align__(16) _Float16 Vsh[128][72];   // [d][key]
  __shared__ __align__(16) _Float16 Psh[4][32][72]; // per-wave [qrow][key]

  const int b = blockIdx.z;
  int qt = blockIdx.x;
  if (b) qt = gridDim.x - 1 - qt;  // heavy/light pairing across CUs
  const int h = blockIdx.y;
  const int tid = threadIdx.x;
  const int wave = tid >> 6, lane = tid & 63;
  const int l16 = lane & 15, quad = lane >> 4;
  const int q0 = qt * 128;
  const int wq0 = q0 + wave * 32;

  half8 qf[2][4];
#pragma unroll
  for (int rb = 0; rb < 2; rb++)
#pragma unroll
    for (int kc = 0; kc < 4; kc++)
      qf[rb][kc] = *(const half8*)(Qh +
          (size_t)(b * 2048 + wq0 + rb * 16 + l16) * 2048 + h * 128 +
          kc * 32 + quad * 8);

  half8 ones;
#pragma unroll
  for (int e = 0; e < 8; e++) ones[e] = (_Float16)1.0f;

  const int kkey = tid >> 2, kd = (tid & 3) * 32;
  const int vd = tid >> 1, vkey = (tid & 1) * 32;

  half8 kpre[4], vpre[4];
  {
    const _Float16* p = Kh + (size_t)(b * 2048 + kkey) * 2048 + h * 128 + kd;
#pragma unroll
    for (int i = 0; i < 4; i++) kpre[i] = *(const half8*)(p + i * 8);
    const _Float16* pv = Vt + ((size_t)b << 22) + (size_t)(h * 128 + vd) * 2048 + vkey;
#pragma unroll
    for (int i = 0; i < 4; i++) vpre[i] = *(const half8*)(pv + i * 8);
  }

  float4v o[2][9] = {};  // [rb][0..7]=O cols, [8]=row-sum accumulator
  float4v mrow[2];
#pragma unroll
  for (int rb = 0; rb < 2; rb++)
#pragma unroll
    for (int e = 0; e < 4; e++) mrow[rb][e] = -INFINITY;

  const int nkb = qt * 2 + 2;  // 64-key tiles
  for (int kb = 0; kb < nkb; kb++) {
    const int k0 = kb * 64;
    __syncthreads();
#pragma unroll
    for (int i = 0; i < 4; i++) *(half8*)&Ksh[kkey][kd + i * 8] = kpre[i];
#pragma unroll
    for (int i = 0; i < 4; i++) *(half8*)&Vsh[vd][vkey + i * 8] = vpre[i];
    __syncthreads();

    if (kb + 1 < nkb) {
      const int k1 = k0 + 64;
      const _Float16* p = Kh + (size_t)(b * 2048 + k1 + kkey) * 2048 + h * 128 + kd;
#pragma unroll
      for (int i = 0; i < 4; i++) kpre[i] = *(const half8*)(p + i * 8);
      const _Float16* pv = Vt + ((size_t)b << 22) + (size_t)(h * 128 + vd) * 2048 + k1 + vkey;
#pragma unroll
      for (int i = 0; i < 4; i++) vpre[i] = *(const half8*)(pv + i * 8);
    }

    if (k0 <= wq0 + 31) {
      float4v s[2][4] = {};
#pragma unroll
      for (int kc = 0; kc < 4; kc++) {
#pragma unroll
        for (int cb = 0; cb < 4; cb++) {
          half8 kf = *(const half8*)&Ksh[cb * 16 + l16][kc * 32 + quad * 8];
#pragma unroll
          for (int rb = 0; rb < 2; rb++)
            s[rb][cb] = __builtin_amdgcn_mfma_f32_16x16x32_f16(qf[rb][kc], kf, s[rb][cb], 0, 0, 0);
        }
      }
      if (k0 + 63 > wq0) {
#pragma unroll
        for (int cb = 0; cb < 4; cb++)
#pragma unroll
          for (int rb = 0; rb < 2; rb++)
#pragma unroll
            for (int reg = 0; reg < 4; reg++) {
              const int key = k0 + cb * 16 + l16;
              const int row = wq0 + rb * 16 + quad * 4 + reg;
              if (key > row) s[rb][cb][reg] = -INFINITY;
            }
      }
#pragma unroll
      for (int rb = 0; rb < 2; rb++) {
        float4v mt;
#pragma unroll
        for (int e = 0; e < 4; e++)
          mt[e] = fmaxf(fmaxf(s[rb][0][e], s[rb][1][e]),
                        fmaxf(s[rb][2][e], s[rb][3][e]));
        int need = 0;
#pragma unroll
        for (int e = 0; e < 4; e++) need |= (mt[e] > mrow[rb][e] + 8.0f) ? 1 : 0;
        if (__any(need)) {  // rare: full row-reduce + rescale only here
#pragma unroll
          for (int msk = 1; msk <= 8; msk <<= 1)
#pragma unroll
            for (int e = 0; e < 4; e++) mt[e] = fmaxf(mt[e], __shfl_xor(mt[e], msk, 64));
          float4v al;
#pragma unroll
          for (int e = 0; e < 4; e++) {
            const float mn = fmaxf(mrow[rb][e], mt[e]);
            al[e] = exp2f(mrow[rb][e] - mn);
            mrow[rb][e] = mn;
          }
#pragma unroll
          for (int cd = 0; cd < 9; cd++)
#pragma unroll
            for (int e = 0; e < 4; e++) o[rb][cd][e] *= al[e];
        }
#pragma unroll
        for (int cb = 0; cb < 4; cb++) {
#pragma unroll
          for (int e = 0; e < 4; e++) s[rb][cb][e] = exp2f(s[rb][cb][e] - mrow[rb][e]);
#pragma unroll
          for (int e = 0; e < 4; e++)
            Psh[wave][rb * 16 + quad * 4 + e][cb * 16 + l16] = (_Float16)s[rb][cb][e];
        }
      }
      half8 pf[2][2];
#pragma unroll
      for (int rb = 0; rb < 2; rb++)
#pragma unroll
        for (int kc = 0; kc < 2; kc++)
          pf[rb][kc] = *(const half8*)&Psh[wave][rb * 16 + l16][kc * 32 + quad * 8];
#pragma unroll
      for (int cd = 0; cd < 8; cd++) {
#pragma unroll
        for (int kc = 0; kc < 2; kc++) {
          half8 vf = *(const half8*)&Vsh[cd * 16 + l16][kc * 32 + quad * 8];
#pragma unroll
          for (int rb = 0; rb < 2; rb++)
            o[rb][cd] = __builtin_amdgcn_mfma_f32_16x16x32_f16(pf[rb][kc], vf, o[rb][cd], 0, 0, 0);
        }
      }
#pragma unroll
      for (int kc = 0; kc < 2; kc++)
#pragma unroll
        for (int rb = 0; rb < 2; rb++)
          o[rb][8] = __builtin_amdgcn_mfma_f32_16x16x32_f16(pf[rb][kc], ones, o[rb][8], 0, 0, 0);
    }
  }

  // ---- finalize: O /= rowsum, write fp16 (direct, R4 style) ----
#pragma unroll
  for (int rb = 0; rb < 2; rb++) {
    float4v inv;
#pragma unroll
    for (int e = 0; e < 4; e++) inv[e] = 1.0f / o[rb][8][e];
#pragma unroll
    for (int cd = 0; cd < 8; cd++)
#pragma unroll
      for (int reg = 0; reg < 4; reg++)
        Oh[(size_t)(b * 2048 + wq0 + rb * 16 + quad * 4 + reg) * 2048 +
           h * 128 + cd * 16 + l16] = (_Float16)(o[rb][cd][reg] * inv[reg]);
  }
}

// ---------------- launcher ----------------------------------------------
extern "C" void kernel_launch(void* const* d_in, const int* in_sizes, int n_in,
                              void* d_out, int out_size, void* d_ws,
                              size_t ws_size, hipStream_t stream) {
  const float* x = (const float*)d_in[0];
  const float* Wq = (const float*)d_in[1];
  const float* Wk = (const float*)d_in[2];
  const float* Wv = (const float*)d_in[3];
  const float* W1 = (const float*)d_in[4];
  const float* b1 = (const float*)d_in[5];
  const float* W2 = (const float*)d_in[6];
  const float* b2 = (const float*)d_in[7];
  float* out = (float*)d_out;

  const int ME = 8388608;  // 4096*2048 (also numel(x))
  const int EE = 4194304;  // 2048*2048

  _Float16* ws = (_Float16*)d_ws;
  _Float16* xh  = ws;                 // 8.4M halves
  _Float16* Wqh = xh + ME;            // 4.2M
  _Float16* Wkh = Wqh + EE;
  _Float16* Wvh = Wkh + EE;
  _Float16* Qh  = Wvh + EE;           // 8.4M
  _Float16* Kh  = Qh + ME;
  _Float16* Vt  = Kh + ME;            // ends at 92.3 MB
  _Float16* Oh  = xh;                 // alias (xh dead after QKV)
  _Float16* W1h = Wqh;                // alias over Wq+Wk (dead after QKV)
  _Float16* W2h = Vt;                 // alias (Vt dead after attention)
  _Float16* Hid = Qh;                 // alias over Qh+Kh (dead after attention)
  float*    P0  = (float*)ws;         // ffn2 f32 partial (xh span, dead then)

  const float qscale = 1.4426950408889634f * 0.08838834764831845f;  // log2e/sqrt(128)

  // convert x (and fold qscale into Wq), Wk, Wv
  cvt_kernel<<<dim3(1024, 4), 256, 0, stream>>>(x, Wq, Wk, Wv, xh, Wqh, Wkh, Wvh,
                                                ME, EE, EE, EE, qscale);
  // QKV projections: one launch, z = 0/1/2  (256x256 tiles)
  gemm_qkv<<<dim3(8, 16, 3), 512, 0, stream>>>(xh, Wqh, Wkh, Wvh, Qh, Kh, Vt);
  // attention
  attn_mfma<<<dim3(16, 16, 2), 256, 0, stream>>>(Qh, Kh, Vt, Oh);
  // convert FFN weights (regions now dead)
  cvt_kernel<<<dim3(1024, 2), 256, 0, stream>>>(W1, W2, nullptr, nullptr,
                                                W1h, W2h, nullptr, nullptr,
                                                ME, ME, 0, 0, 1.0f);
  // FFN1
  gemm_ffn1<<<dim3(16, 16), 512, 0, stream>>>(Oh, W1h, b1, Hid, 4096, 2048);
  // FFN2: split-K x2 (256 blocks, full machine) + reduce with bias
  gemm_ffn2_part<<<dim3(8, 16, 2), 512, 0, stream>>>(Hid, W2h, P0, out);
  reduce_add<<<dim3(2048), 256, 0, stream>>>(out, P0, b2, ME);
}

// Round 10
// 529.575 us; speedup vs baseline: 1.4752x; 1.0203x over previous
//
#include <hip/hip_runtime.h>
#include <cmath>

// B=2, S=2048, E=2048, H=16, D=128, M=B*S=4096, F=2E=4096
// Round-10 = R9 (verified 540us) + two dispatch-boundary recoveries:
// (1) cvt of W1/W2 fused into the qkv grid as 128 extra blocks (z=3):
//     qkv is 384 blocks = 2 rounds at 1 block/CU; the extra cvt blocks
//     (each ~32us < GEMM block ~71us) hide in the half-empty 2nd round.
//     Requires W1h/W2h in FRESH workspace (no alias with live Wq/Vt) ->
//     runtime ws_size check with full R9 fallback.
// (2) reduce_add deleted: ffn2 split-K partials atomicAdd into out
//     (harness memsets out=0; exactly 2 contributions/address; fp add
//     commutative -> deterministic; z=0 folds bias).

typedef _Float16 half8 __attribute__((ext_vector_type(8)));
typedef _Float16 half4v __attribute__((ext_vector_type(4)));
typedef float float4v __attribute__((ext_vector_type(4)));

__device__ inline void load_lds16(const _Float16* g, _Float16* l) {
  __builtin_amdgcn_global_load_lds(
      (const __attribute__((address_space(1))) void*)g,
      (__attribute__((address_space(3))) void*)l, 16, 0, 0);
}

// ---------------- fp32 -> fp16 convert (up to 4 arrays per launch) -------
__global__ void cvt_kernel(const float* __restrict__ s0, const float* __restrict__ s1,
                           const float* __restrict__ s2, const float* __restrict__ s3,
                           _Float16* d0, _Float16* d1, _Float16* d2, _Float16* d3,
                           int n0, int n1, int n2, int n3, float sc1) {
  const float* s;
  _Float16* d;
  int n;
  float sc = 1.0f;
  switch (blockIdx.y) {
    case 0: s = s0; d = d0; n = n0; break;
    case 1: s = s1; d = d1; n = n1; sc = sc1; break;
    case 2: s = s2; d = d2; n = n2; break;
    default: s = s3; d = d3; n = n3; break;
  }
  const int step = gridDim.x * 256 * 4;
  for (int i = (blockIdx.x * 256 + threadIdx.x) * 4; i < n; i += step) {
    float4v v = *(const float4v*)&s[i];
    half4v h;
#pragma unroll
    for (int e = 0; e < 4; e++) h[e] = (_Float16)(v[e] * sc);
    *(half4v*)&d[i] = h;
  }
}

// ---------------- 8-phase 256x256 GEMM core (round-2 schedule) -----------
__device__ __forceinline__ void gemm8_core(
    const _Float16* __restrict__ A, const _Float16* __restrict__ B, int Kloop,
    int Kstride, int bm, int bn, _Float16* lds, float4v acc[8][4]) {
  const int tid = threadIdx.x;
  const int w = tid >> 6, lane = tid & 63;
  const int l16 = lane & 15, quad = lane >> 4;
  const int srow = w * 16 + (lane >> 2);
  const int clocal = ((lane & 3) * 8) ^ ((lane & 32) ? 16 : 0);
  int rdh = (l16 << 5) + (quad << 3);
  rdh ^= (l16 & 8) << 1;  // st_16x32: ^32B when row&8

  const _Float16* pA0 = A + (size_t)(bm + srow) * Kstride + clocal;
  const _Float16* pA1 = A + (size_t)(bm + 128 + srow) * Kstride + clocal;
  const _Float16* pB0 = B + (size_t)(bn + srow) * Kstride + clocal;
  const _Float16* pB1 = B + (size_t)(bn + 128 + srow) * Kstride + clocal;

  _Float16* const dA0 = lds + w * 1024;
  _Float16* const dA1 = lds + 8192 + w * 1024;
  _Float16* const dB0 = lds + 16384 + w * 1024;
  _Float16* const dB1 = lds + 24576 + w * 1024;

  const int aH = w >> 2, bH = (w >> 1) & 1, bRB = (w & 1) * 4;
  const _Float16* const rA0 = lds + aH * 8192;
  const _Float16* const rB0 = lds + 16384 + bH * 8192;
  const _Float16* const rA1 = rA0 + 32768;
  const _Float16* const rB1 = rB0 + 32768;

  const int NT = Kloop >> 6;  // 64-wide K tiles (always even here)

#define STG(p, d, kt)                     \
  do {                                    \
    const _Float16* _s = (p) + (kt) * 64; \
    load_lds16(_s, (d));                  \
    load_lds16(_s + 32, (d) + 512);       \
  } while (0)
#define BARRIER() asm volatile("s_barrier" ::: "memory")
#define WAIT_LGKM()                                  \
  asm volatile("s_waitcnt lgkmcnt(0)" ::: "memory"); \
  __builtin_amdgcn_sched_barrier(0);
#define RD_A(base, RB0)                                                       \
  _Pragma("unroll") for (int rb = 0; rb < 4; rb++)                            \
  _Pragma("unroll") for (int ks = 0; ks < 2; ks++)                            \
      af[rb][ks] = *(const half8*)&(base)[((((RB0) + rb) * 2 + ks) << 9) + rdh];
#define RD_B(base, J0)                                                        \
  _Pragma("unroll") for (int j = 0; j < 2; j++)                               \
  _Pragma("unroll") for (int ks = 0; ks < 2; ks++)                            \
      bf[(J0) + j][ks] =                                                      \
          *(const half8*)&(base)[(((bRB + (J0) + j) * 2 + ks) << 9) + rdh];
#define MFMA_Q(RB0, J0)                                                       \
  __builtin_amdgcn_s_setprio(1);                                              \
  _Pragma("unroll") for (int rb = 0; rb < 4; rb++)                            \
  _Pragma("unroll") for (int j = 0; j < 2; j++)                               \
  _Pragma("unroll") for (int ks = 0; ks < 2; ks++)                            \
      acc[(RB0) + rb][(J0) + j] = __builtin_amdgcn_mfma_f32_16x16x32_f16(     \
          af[rb][ks], bf[(J0) + j][ks], acc[(RB0) + rb][(J0) + j], 0, 0, 0);  \
  __builtin_amdgcn_s_setprio(0);                                              \
  BARRIER();

  // prologue: tile0 {B0,B1,A0,A1} + tile1 {B0,B1}; retire tile0 (8 instr)
  STG(pB0, dB0, 0); STG(pB1, dB1, 0); STG(pA0, dA0, 0); STG(pA1, dA1, 0);
  STG(pB0, dB0 + 32768, 1); STG(pB1, dB1 + 32768, 1);
  asm volatile("s_waitcnt vmcnt(4)" ::: "memory");
  BARRIER();

  half8 af[4][2], bf[4][2];

  for (int t = 0; t < NT; t += 2) {
    const bool last = (t + 2 >= NT);
    // ---- tile t (buf0) ----
    RD_A(rA0, 0) RD_B(rB0, 0)
    STG(pA0, dA0 + 32768, t + 1);
    BARRIER(); WAIT_LGKM()
    MFMA_Q(0, 0)
    RD_B(rB0, 2)
    STG(pA1, dA1 + 32768, t + 1);
    BARRIER(); WAIT_LGKM()
    MFMA_Q(0, 2)
    RD_A(rA0, 4)
    if (!last) STG(pB0, dB0, t + 2);
    BARRIER(); WAIT_LGKM()
    MFMA_Q(4, 0)
    if (!last) {
      STG(pA0, dA0, t + 2);
      asm volatile("s_waitcnt vmcnt(4)" ::: "memory");
    } else {
      asm volatile("s_waitcnt vmcnt(0)" ::: "memory");
    }
    BARRIER();
    MFMA_Q(4, 2)
    // ---- tile t+1 (buf1) ----
    RD_A(rA1, 0) RD_B(rB1, 0)
    if (!last) STG(pA1, dA1, t + 2);
    BARRIER(); WAIT_LGKM()
    MFMA_Q(0, 0)
    RD_B(rB1, 2)
    if (!last) STG(pB1, dB1, t + 2);
    BARRIER(); WAIT_LGKM()
    MFMA_Q(0, 2)
    RD_A(rA1, 4)
    if (!last) STG(pB0, dB0 + 32768, t + 3);
    BARRIER(); WAIT_LGKM()
    MFMA_Q(4, 0)
    if (!last) {
      STG(pB1, dB1 + 32768, t + 3);
      asm volatile("s_waitcnt vmcnt(4)" ::: "memory");
    }
    BARRIER();
    MFMA_Q(4, 2)
  }
#undef STG
#undef BARRIER
#undef WAIT_LGKM
#undef RD_A
#undef RD_B
#undef MFMA_Q
}

// ---------------- QKV: z = 0(Q)/1(K)/2(V transposed)/3(fused W-cvt) ------
__global__ __launch_bounds__(512, 2) void gemm_qkv(
    const _Float16* __restrict__ xh, const _Float16* __restrict__ Wq,
    const _Float16* __restrict__ Wk, const _Float16* __restrict__ Wv,
    _Float16* __restrict__ Qh, _Float16* __restrict__ Kh,
    _Float16* __restrict__ Vt, const float* __restrict__ W1f,
    const float* __restrict__ W2f, _Float16* __restrict__ W1h,
    _Float16* __restrict__ W2h) {
  __shared__ __align__(16) _Float16 lds[67584];  // 132 KiB (V-Tr needs 256*264)
  const int z = blockIdx.z;
  const int tid = threadIdx.x;
  if (z == 3) {
    // fused FFN-weight conversion: 128 blocks x 512 thr, f32x4 stride loop
    const int bidx = blockIdx.x + (blockIdx.y << 3);  // 0..127
    const int step = 128 * 512 * 4;
    for (int i = (bidx * 512 + tid) * 4; i < 8388608; i += step) {
      float4v v1 = *(const float4v*)&W1f[i];
      float4v v2 = *(const float4v*)&W2f[i];
      half4v h1, h2;
#pragma unroll
      for (int e = 0; e < 4; e++) { h1[e] = (_Float16)v1[e]; h2[e] = (_Float16)v2[e]; }
      *(half4v*)&W1h[i] = h1;
      *(half4v*)&W2h[i] = h2;
    }
    return;
  }
  const _Float16* B = (z == 0) ? Wq : (z == 1 ? Wk : Wv);
  const int bm = blockIdx.y * 256, bn = blockIdx.x * 256;
  float4v acc[8][4] = {};
  gemm8_core(xh, B, 2048, 2048, bm, bn, lds, acc);

  const int w = tid >> 6, lane = tid & 63;
  const int l16 = lane & 15, quad = lane >> 4;
  const int wm = (w >> 2) * 128, wn = (w & 3) * 64;
  if (z == 2) {
    // V: transpose through LDS -> coalesced 16B column-major stores.
    _Float16* Tr = lds;  // [col][m], stride 264 halves
    __syncthreads();
#pragma unroll
    for (int j = 0; j < 4; j++) {
      const int cl = wn + j * 16 + l16;
#pragma unroll
      for (int rb = 0; rb < 8; rb++) {
        const int ml = wm + rb * 16 + quad * 4;
#pragma unroll
        for (int reg = 0; reg < 4; reg++)
          Tr[cl * 264 + ml + reg] = (_Float16)acc[rb][j][reg];
      }
    }
    __syncthreads();
    const int cl = tid >> 1;
    const int ml = (tid & 1) * 128;
    const int mg = bm + ml;
    _Float16* dst = Vt + ((size_t)(mg >> 11) << 22) +
                    ((size_t)(bn + cl) << 11) + (mg & 2047);
#pragma unroll
    for (int i = 0; i < 16; i++)
      *(half8*)(dst + i * 8) = *(const half8*)&Tr[cl * 264 + ml + i * 8];
  } else {
    _Float16* outRM = z ? Kh : Qh;
#pragma unroll
    for (int j = 0; j < 4; j++) {
      const int col = bn + wn + j * 16 + l16;
#pragma unroll
      for (int rb = 0; rb < 8; rb++) {
        const int rbase = bm + wm + rb * 16 + quad * 4;
#pragma unroll
        for (int reg = 0; reg < 4; reg++)
          outRM[(size_t)(rbase + reg) * 2048 + col] = (_Float16)acc[rb][j][reg];
      }
    }
  }
}

// ---------------- FFN1 GEMM (GELU sigmoid-form, f16 out, direct) ---------
__global__ __launch_bounds__(512, 2) void gemm_ffn1(
    const _Float16* __restrict__ A, const _Float16* __restrict__ B,
    const float* __restrict__ bias, _Float16* __restrict__ out, int N, int K) {
  __shared__ __align__(16) _Float16 lds[65536];
  const int bm = blockIdx.y * 256, bn = blockIdx.x * 256;
  float4v acc[8][4] = {};
  gemm8_core(A, B, K, K, bm, bn, lds, acc);

  const int tid = threadIdx.x;
  const int w = tid >> 6, lane = tid & 63;
  const int l16 = lane & 15, quad = lane >> 4;
  const int wm = (w >> 2) * 128, wn = (w & 3) * 64;
#pragma unroll
  for (int j = 0; j < 4; j++) {
    const int col = bn + wn + j * 16 + l16;
    const float bv = bias[col];
#pragma unroll
    for (int rb = 0; rb < 8; rb++) {
      const int rbase = bm + wm + rb * 16 + quad * 4;
#pragma unroll
      for (int reg = 0; reg < 4; reg++) {
        const int m = rbase + reg;
        const float x = acc[rb][j][reg] + bv;
        const float t = x + 0.044715f * x * x * x;
        const float e = exp2f(-2.302208198f * t);  // exp(-1.59576912*t)
        out[(size_t)m * N + col] = (_Float16)(x / (1.0f + e));
      }
    }
  }
}

// ---------------- FFN2 split-K GEMM, atomic accumulate into out ----------
// z selects K-half; out is memset to 0 by the harness before launch.
// Exactly 2 contributions per element (+bias from z=0); fp add is
// commutative so the result is order-independent.
__global__ __launch_bounds__(512, 2) void gemm_ffn2_atomic(
    const _Float16* __restrict__ A, const _Float16* __restrict__ B,
    const float* __restrict__ bias, float* __restrict__ out) {
  __shared__ __align__(16) _Float16 lds[65536];
  const int bm = blockIdx.y * 256, bn = blockIdx.x * 256;
  const int k0 = blockIdx.z * 2048;
  float4v acc[8][4] = {};
  gemm8_core(A + k0, B + k0, 2048, 4096, bm, bn, lds, acc);

  const int tid = threadIdx.x;
  const int w = tid >> 6, lane = tid & 63;
  const int l16 = lane & 15, quad = lane >> 4;
  const int wm = (w >> 2) * 128, wn = (w & 3) * 64;
#pragma unroll
  for (int j = 0; j < 4; j++) {
    const int col = bn + wn + j * 16 + l16;
    const float bv = blockIdx.z ? 0.0f : bias[col];
#pragma unroll
    for (int rb = 0; rb < 8; rb++) {
      const int rbase = bm + wm + rb * 16 + quad * 4;
#pragma unroll
      for (int reg = 0; reg < 4; reg++)
        atomicAdd(&out[(size_t)(rbase + reg) * 2048 + col],
                  acc[rb][j][reg] + bv);
    }
  }
}

// ---------------- fp16 MFMA flash attention (R4 structure) ---------------
// One block per (b, h, 128-row q-tile); 4 waves x 32 q-rows; KVBLK=64;
// padded LDS strides (2-way-free banks); 2 blocks/CU (R8 showed 3/CU
// destroys L2 K/V reuse: FETCH 85->336MB). Qh pre-scaled by log2e/sqrt(D).
// Rowsum via mfma(P, ones); deferred rescale (THR=8): shuffle max-tree
// runs only on rescale tiles (trigger equivalent wave-wide).
__global__ __launch_bounds__(256, 2) void attn_mfma(
    const _Float16* __restrict__ Qh, const _Float16* __restrict__ Kh,
    const _Float16* __restrict__ Vt, _Float16* __restrict__ Oh) {
  __shared__ __align__(16) _Float16 Ksh[64][136];   // [key][d]
  __shared__ __align__(16) _Float16 Vsh[128][72];   // [d][key]
  __shared__ __align__(16) _Float16 Psh[4][32][72]; // per-wave [qrow][key]

  const int b = blockIdx.z;
  int qt = blockIdx.x;
  if (b) qt = gridDim.x - 1 - qt;  // heavy/light pairing across CUs
  const int h = blockIdx.y;
  const int tid = threadIdx.x;
  const int wave = tid >> 6, lane = tid & 63;
  const int l16 = lane & 15, quad = lane >> 4;
  const int q0 = qt * 128;
  const int wq0 = q0 + wave * 32;

  half8 qf[2][4];
#pragma unroll
  for (int rb = 0; rb < 2; rb++)
#pragma unroll
    for (int kc = 0; kc < 4; kc++)
      qf[rb][kc] = *(const half8*)(Qh +
          (size_t)(b * 2048 + wq0 + rb * 16 + l16) * 2048 + h * 128 +
          kc * 32 + quad * 8);

  half8 ones;
#pragma unroll
  for (int e = 0; e < 8; e++) ones[e] = (_Float16)1.0f;

  const int kkey = tid >> 2, kd = (tid & 3) * 32;
  const int vd = tid >> 1, vkey = (tid & 1) * 32;

  half8 kpre[4], vpre[4];
  {
    const _Float16* p = Kh + (size_t)(b * 2048 + kkey) * 2048 + h * 128 + kd;
#pragma unroll
    for (int i = 0; i < 4; i++) kpre[i] = *(const half8*)(p + i * 8);
    const _Float16* pv = Vt + ((size_t)b << 22) + (size_t)(h * 128 + vd) * 2048 + vkey;
#pragma unroll
    for (int i = 0; i < 4; i++) vpre[i] = *(const half8*)(pv + i * 8);
  }

  float4v o[2][9] = {};  // [rb][0..7]=O cols, [8]=row-sum accumulator
  float4v mrow[2];
#pragma unroll
  for (int rb = 0; rb < 2; rb++)
#pragma unroll
    for (int e = 0; e < 4; e++) mrow[rb][e] = -INFINITY;

  const int nkb = qt * 2 + 2;  // 64-key tiles
  for (int kb = 0; kb < nkb; kb++) {
    const int k0 = kb * 64;
    __syncthreads();
#pragma unroll
    for (int i = 0; i < 4; i++) *(half8*)&Ksh[kkey][kd + i * 8] = kpre[i];
#pragma unroll
    for (int i = 0; i < 4; i++) *(half8*)&Vsh[vd][vkey + i * 8] = vpre[i];
    __syncthreads();

    if (kb + 1 < nkb) {
      const int k1 = k0 + 64;
      const _Float16* p = Kh + (size_t)(b * 2048 + k1 + kkey) * 2048 + h * 128 + kd;
#pragma unroll
      for (int i = 0; i < 4; i++) kpre[i] = *(const half8*)(p + i * 8);
      const _Float16* pv = Vt + ((size_t)b << 22) + (size_t)(h * 128 + vd) * 2048 + k1 + vkey;
#pragma unroll
      for (int i = 0; i < 4; i++) vpre[i] = *(const half8*)(pv + i * 8);
    }

    if (k0 <= wq0 + 31) {
      float4v s[2][4] = {};
#pragma unroll
      for (int kc = 0; kc < 4; kc++) {
#pragma unroll
        for (int cb = 0; cb < 4; cb++) {
          half8 kf = *(const half8*)&Ksh[cb * 16 + l16][kc * 32 + quad * 8];
#pragma unroll
          for (int rb = 0; rb < 2; rb++)
            s[rb][cb] = __builtin_amdgcn_mfma_f32_16x16x32_f16(qf[rb][kc], kf, s[rb][cb], 0, 0, 0);
        }
      }
      if (k0 + 63 > wq0) {
#pragma unroll
        for (int cb = 0; cb < 4; cb++)
#pragma unroll
          for (int rb = 0; rb < 2; rb++)
#pragma unroll
            for (int reg = 0; reg < 4; reg++) {
              const int key = k0 + cb * 16 + l16;
              const int row = wq0 + rb * 16 + quad * 4 + reg;
              if (key > row) s[rb][cb][reg] = -INFINITY;
            }
      }
#pragma unroll
      for (int rb = 0; rb < 2; rb++) {
        float4v mt;
#pragma unroll
        for (int e = 0; e < 4; e++)
          mt[e] = fmaxf(fmaxf(s[rb][0][e], s[rb][1][e]),
                        fmaxf(s[rb][2][e], s[rb][3][e]));
        int need = 0;
#pragma unroll
        for (int e = 0; e < 4; e++) need |= (mt[e] > mrow[rb][e] + 8.0f) ? 1 : 0;
        if (__any(need)) {  // rare: full row-reduce + rescale only here
#pragma unroll
          for (int msk = 1; msk <= 8; msk <<= 1)
#pragma unroll
            for (int e = 0; e < 4; e++) mt[e] = fmaxf(mt[e], __shfl_xor(mt[e], msk, 64));
          float4v al;
#pragma unroll
          for (int e = 0; e < 4; e++) {
            const float mn = fmaxf(mrow[rb][e], mt[e]);
            al[e] = exp2f(mrow[rb][e] - mn);
            mrow[rb][e] = mn;
          }
#pragma unroll
          for (int cd = 0; cd < 9; cd++)
#pragma unroll
            for (int e = 0; e < 4; e++) o[rb][cd][e] *= al[e];
        }
#pragma unroll
        for (int cb = 0; cb < 4; cb++) {
#pragma unroll
          for (int e = 0; e < 4; e++) s[rb][cb][e] = exp2f(s[rb][cb][e] - mrow[rb][e]);
#pragma unroll
          for (int e = 0; e < 4; e++)
            Psh[wave][rb * 16 + quad * 4 + e][cb * 16 + l16] = (_Float16)s[rb][cb][e];
        }
      }
      half8 pf[2][2];
#pragma unroll
      for (int rb = 0; rb < 2; rb++)
#pragma unroll
        for (int kc = 0; kc < 2; kc++)
          pf[rb][kc] = *(const half8*)&Psh[wave][rb * 16 + l16][kc * 32 + quad * 8];
#pragma unroll
      for (int cd = 0; cd < 8; cd++) {
#pragma unroll
        for (int kc = 0; kc < 2; kc++) {
          half8 vf = *(const half8*)&Vsh[cd * 16 + l16][kc * 32 + quad * 8];
#pragma unroll
          for (int rb = 0; rb < 2; rb++)
            o[rb][cd] = __builtin_amdgcn_mfma_f32_16x16x32_f16(pf[rb][kc], vf, o[rb][cd], 0, 0, 0);
        }
      }
#pragma unroll
      for (int kc = 0; kc < 2; kc++)
#pragma unroll
        for (int rb = 0; rb < 2; rb++)
          o[rb][8] = __builtin_amdgcn_mfma_f32_16x16x32_f16(pf[rb][kc], ones, o[rb][8], 0, 0, 0);
    }
  }

  // ---- finalize: O /= rowsum, write fp16 (direct, R4 style) ----
#pragma unroll
  for (int rb = 0; rb < 2; rb++) {
    float4v inv;
#pragma unroll
    for (int e = 0; e < 4; e++) inv[e] = 1.0f / o[rb][8][e];
#pragma unroll
    for (int cd = 0; cd < 8; cd++)
#pragma unroll
      for (int reg = 0; reg < 4; reg++)
        Oh[(size_t)(b * 2048 + wq0 + rb * 16 + quad * 4 + reg) * 2048 +
           h * 128 + cd * 16 + l16] = (_Float16)(o[rb][cd][reg] * inv[reg]);
  }
}

// ---------------- launcher ----------------------------------------------
extern "C" void kernel_launch(void* const* d_in, const int* in_sizes, int n_in,
                              void* d_out, int out_size, void* d_ws,
                              size_t ws_size, hipStream_t stream) {
  const float* x = (const float*)d_in[0];
  const float* Wq = (const float*)d_in[1];
  const float* Wk = (const float*)d_in[2];
  const float* Wv = (const float*)d_in[3];
  const float* W1 = (const float*)d_in[4];
  const float* b1 = (const float*)d_in[5];
  const float* W2 = (const float*)d_in[6];
  const float* b2 = (const float*)d_in[7];
  float* out = (float*)d_out;

  const int ME = 8388608;  // 4096*2048 (also numel(x))
  const int EE = 4194304;  // 2048*2048

  _Float16* ws = (_Float16*)d_ws;
  _Float16* xh  = ws;                 // 8.4M halves
  _Float16* Wqh = xh + ME;            // 4.2M
  _Float16* Wkh = Wqh + EE;
  _Float16* Wvh = Wkh + EE;
  _Float16* Qh  = Wvh + EE;           // 8.4M
  _Float16* Kh  = Qh + ME;
  _Float16* Vt  = Kh + ME;            // ends at 92.3 MB
  _Float16* Oh  = xh;                 // alias (xh dead after QKV)
  _Float16* Hid = Qh;                 // alias over Qh+Kh (dead after attention)

  // fused path needs fresh (non-aliased) W1h/W2h: 92.3MB + 33.6MB = 125.9MB
  const size_t need = ((size_t)ME * 4 + (size_t)EE * 3 + (size_t)ME * 2) * 2;
  const bool fused = ws_size >= need;
  _Float16* W1h = fused ? (Vt + ME) : Wqh;        // fresh | alias Wq+Wk
  _Float16* W2h = fused ? (Vt + ME + ME) : Vt;    // fresh | alias Vt

  const float qscale = 1.4426950408889634f * 0.08838834764831845f;  // log2e/sqrt(128)

  // convert x (and fold qscale into Wq), Wk, Wv
  cvt_kernel<<<dim3(1024, 4), 256, 0, stream>>>(x, Wq, Wk, Wv, xh, Wqh, Wkh, Wvh,
                                                ME, EE, EE, EE, qscale);
  // QKV projections (+ fused W1/W2 convert when workspace allows)
  gemm_qkv<<<dim3(8, 16, fused ? 4 : 3), 512, 0, stream>>>(
      xh, Wqh, Wkh, Wvh, Qh, Kh, Vt, W1, W2, W1h, W2h);
  // attention
  attn_mfma<<<dim3(16, 16, 2), 256, 0, stream>>>(Qh, Kh, Vt, Oh);
  // FFN-weight convert (only if not fused into qkv)
  if (!fused)
    cvt_kernel<<<dim3(1024, 2), 256, 0, stream>>>(W1, W2, nullptr, nullptr,
                                                  W1h, W2h, nullptr, nullptr,
                                                  ME, ME, 0, 0, 1.0f);
  // FFN1
  gemm_ffn1<<<dim3(16, 16), 512, 0, stream>>>(Oh, W1h, b1, Hid, 4096, 2048);
  // FFN2: split-K x2, atomic accumulate into out (harness memsets out=0)
  gemm_ffn2_atomic<<<dim3(8, 16, 2), 512, 0, stream>>>(Hid, W2h, b2, out);
}